// Round 2
// baseline (826.719 us; speedup 1.0000x reference)
//
#include <hip/hip_runtime.h>
#include <hip/hip_bf16.h>
#include <cstdint>
#include <cstddef>

typedef unsigned short u16;
typedef __attribute__((ext_vector_type(8))) __bf16 bf16x8;
typedef __attribute__((ext_vector_type(4))) float f32x4;

#define EPS_BN 1e-5f

__device__ __forceinline__ u16 f2bf(float f) {
    union { float f; uint32_t u; } v; v.f = f;
    uint32_t u = v.u;
    u += 0x7FFFu + ((u >> 16) & 1u);   // round-to-nearest-even
    return (u16)(u >> 16);
}
__device__ __forceinline__ float bf2f(u16 s) {
    union { uint32_t u; float f; } v; v.u = ((uint32_t)s) << 16;
    return v.f;
}

union Pack8 { u16 u[8]; uint4 v4; };
union Pack4 { u16 u[4]; uint2 v2; };

// ---------------------------------------------------------------------------
// Transpose NCHW fp32 -> NHWC bf16.  One thread per pixel; 256-ch loop.
// Reads coalesced (lanes = consecutive pixels, per-channel); writes 16B/lane.
// ---------------------------------------------------------------------------
__global__ __launch_bounds__(256)
void tr_nchw_nhwc(const float* __restrict__ in, u16* __restrict__ out,
                  int P, int total)
{
    int p = blockIdx.x * 256 + threadIdx.x;
    if (p >= total) return;
    int b = p / P, pp = p - b * P;
    const float* ip = in + (size_t)b * 256 * P + pp;
    u16* op = out + (size_t)p * 256;
    #pragma unroll 4
    for (int cg = 0; cg < 32; cg++) {
        Pack8 pk;
        #pragma unroll
        for (int i = 0; i < 8; i++)
            pk.u[i] = f2bf(ip[(size_t)(cg * 8 + i) * P]);
        *(uint4*)(op + cg * 8) = pk.v4;
    }
}

// ---------------------------------------------------------------------------
// Implicit-im2col GEMM, NHWC bf16 input:
//   out[oc, (b,oy,ox)] = sum_k W[oc,k] * X[(b,oy,ox), k],  k = (tap, c)
// 128x128 tile, BK=64, 4 waves, 4x4 frags of 16x16x32 bf16 MFMA.
// B staging: 4 x dwordx4 contiguous-channel loads per thread per kb.
// ---------------------------------------------------------------------------
template<int TAPS, bool NHWC_OUT, typename OutT, bool RELU>
__global__ __launch_bounds__(256)
void conv_gemm(const u16* __restrict__ in, const u16* __restrict__ W,
               const float* __restrict__ scale, const float* __restrict__ shift,
               OutT* __restrict__ out, int Hi, int Wi, int Ho, int Wo)
{
    constexpr int KT = TAPS * 256;
    constexpr int KB = KT / 64;
    const int HoWo = Ho * Wo;

    __shared__ u16 Alds[128 * 64];
    __shared__ u16 Blds[128 * 64];

    const int tid = threadIdx.x;
    const int it = blockIdx.x;   // I tile (oc): 0..1
    const int jt = blockIdx.y;   // J tile

    // ---- B staging coords: thread -> fixed output pixel, contiguous channels
    const int jl = tid & 127;
    const int kh = tid >> 7;           // which 32-k half
    const int jg = jt * 128 + jl;
    const int bb = jg / HoWo;
    const int msp = jg - bb * HoWo;
    const int oy = msp / Wo;
    const int ox = msp - oy * Wo;
    const size_t pixbase = ((size_t)(bb * Hi + oy) * Wi + ox) * 256;

    // ---- MFMA coords
    const int lane = tid & 63;
    const int wv = tid >> 6;
    const int wi = (wv >> 1) * 64;
    const int wj = (wv & 1) * 64;
    const int lr = lane & 15;
    const int lq = lane >> 4;

    f32x4 acc[4][4];
    #pragma unroll
    for (int a = 0; a < 4; a++)
        #pragma unroll
        for (int b = 0; b < 4; b++)
            acc[a][b] = (f32x4){0.f, 0.f, 0.f, 0.f};

    for (int kb = 0; kb < KB; kb++) {
        const int tap = (TAPS == 1) ? 0 : (kb >> 2);
        const int c0  = (TAPS == 1) ? (kb * 64) : ((kb & 3) * 64);
        __syncthreads();
        // ---- stage A (weights): 128 rows x 64 k, 16B chunks
        {
            const u16* Wb = W + (size_t)(it * 128) * KT + tap * 256 + c0;
            #pragma unroll
            for (int q = 0; q < 4; q++) {
                int g = q * 256 + tid;
                int row = g >> 3, cc = g & 7;
                uint4 v = *(const uint4*)(Wb + (size_t)row * KT + cc * 8);
                *(uint4*)&Alds[row * 64 + ((cc ^ (row & 7)) * 8)] = v;
            }
        }
        // ---- stage B (activations): contiguous-channel 16B loads
        {
            int ky = 0, kx = 0;
            if (TAPS == 9) { ky = tap / 3; kx = tap - ky * 3; }
            const u16* p0 = in + pixbase + (size_t)(ky * Wi + kx) * 256
                               + c0 + kh * 32;
            #pragma unroll
            for (int c4 = 0; c4 < 4; c4++) {
                uint4 v = *(const uint4*)(p0 + c4 * 8);
                int ck = kh * 4 + c4;
                *(uint4*)&Blds[jl * 64 + ((ck ^ (jl & 7)) * 8)] = v;
            }
        }
        __syncthreads();
        // ---- MFMA: 2 k-steps of 32
        #pragma unroll
        for (int ks = 0; ks < 2; ks++) {
            bf16x8 af[4], bfr[4];
            const int ck = ks * 4 + lq;
            #pragma unroll
            for (int f = 0; f < 4; f++) {
                int ra = wi + f * 16 + lr;
                af[f]  = *(const bf16x8*)&Alds[ra * 64 + ((ck ^ (ra & 7)) * 8)];
                int rb = wj + f * 16 + lr;
                bfr[f] = *(const bf16x8*)&Blds[rb * 64 + ((ck ^ (rb & 7)) * 8)];
            }
            #pragma unroll
            for (int fi = 0; fi < 4; fi++)
                #pragma unroll
                for (int fj = 0; fj < 4; fj++)
                    acc[fi][fj] = __builtin_amdgcn_mfma_f32_16x16x32_bf16(
                        af[fi], bfr[fj], acc[fi][fj], 0, 0, 0);
        }
    }

    // ---- epilogue: BN (scale/shift) + optional ReLU
    if constexpr (NHWC_OUT) {
        // out[(pixel)*256 + oc], 4 contiguous oc per lane -> 8B stores
        int jc[4];
        #pragma unroll
        for (int fj = 0; fj < 4; fj++) jc[fj] = jt * 128 + wj + fj * 16 + lr;
        #pragma unroll
        for (int fi = 0; fi < 4; fi++) {
            int rb = it * 128 + wi + fi * 16 + lq * 4;
            f32x4 sc = *(const f32x4*)&scale[rb];
            f32x4 sh = *(const f32x4*)&shift[rb];
            #pragma unroll
            for (int fj = 0; fj < 4; fj++) {
                Pack4 pk;
                #pragma unroll
                for (int reg = 0; reg < 4; reg++) {
                    float v = acc[fi][fj][reg] * sc[reg] + sh[reg];
                    if (RELU) v = fmaxf(v, 0.f);
                    pk.u[reg] = f2bf(v);
                }
                *(uint2*)&((u16*)out)[(size_t)jc[fj] * 256 + rb] = pk.v2;
            }
        }
    } else {
        // NCHW fp32 output (final stage)
        int jcb[4], jcm[4];
        #pragma unroll
        for (int fj = 0; fj < 4; fj++) {
            int jc = jt * 128 + wj + fj * 16 + lr;
            int b = jc / HoWo;
            jcb[fj] = b; jcm[fj] = jc - b * HoWo;
        }
        #pragma unroll
        for (int fi = 0; fi < 4; fi++) {
            int rb = it * 128 + wi + fi * 16 + lq * 4;
            f32x4 sc = *(const f32x4*)&scale[rb];
            f32x4 sh = *(const f32x4*)&shift[rb];
            #pragma unroll
            for (int reg = 0; reg < 4; reg++) {
                int r = rb + reg;
                #pragma unroll
                for (int fj = 0; fj < 4; fj++) {
                    float v = acc[fi][fj][reg] * sc[reg] + sh[reg];
                    if (RELU) v = fmaxf(v, 0.f);
                    size_t o = ((size_t)(jcb[fj] * 256 + r)) * HoWo + jcm[fj];
                    ((float*)out)[o] = v;
                }
            }
        }
    }
}

// ---------------------------------------------------------------------------
// Depthwise xcorr, NHWC: feat[b,oy,ox,c] = sum_{5x5} s[b,oy+dy,ox+dx,c]*k[b,dy,dx,c]
// grid (b*25), thread = channel; rows register-resident.
// ---------------------------------------------------------------------------
__global__ __launch_bounds__(256)
void xcorr_kernel(const u16* __restrict__ s, const u16* __restrict__ k,
                  u16* __restrict__ out)
{
    const int b = blockIdx.x / 25;
    const int oy = blockIdx.x - b * 25;
    const int c = threadIdx.x;

    float kf[25];
    #pragma unroll
    for (int t = 0; t < 25; t++)
        kf[t] = bf2f(k[((size_t)(b * 25 + t)) * 256 + c]);

    float acc[25];
    #pragma unroll
    for (int i = 0; i < 25; i++) acc[i] = 0.f;

    for (int dy = 0; dy < 5; dy++) {
        float row[29];
        const u16* sp = s + ((size_t)(b * 29 + oy + dy) * 29) * 256 + c;
        #pragma unroll
        for (int x = 0; x < 29; x++) row[x] = bf2f(sp[(size_t)x * 256]);
        #pragma unroll
        for (int dx = 0; dx < 5; dx++) {
            float kv = kf[dy * 5 + dx];
            #pragma unroll
            for (int ox = 0; ox < 25; ox++)
                acc[ox] += row[ox + dx] * kv;
        }
    }
    u16* op = out + ((size_t)(b * 25 + oy) * 25) * 256 + c;
    #pragma unroll
    for (int ox = 0; ox < 25; ox++)
        op[(size_t)ox * 256] = f2bf(acc[ox]);
}

// ---------------------------------------------------------------------------
// Weight prep: OIHW fp32 -> [oc][tap][c] bf16 (3x3) / direct convert (1x1)
// ---------------------------------------------------------------------------
__global__ void prep_w3(const float* __restrict__ w, u16* __restrict__ o)
{
    int idx = blockIdx.x * 256 + threadIdx.x;
    if (idx >= 256 * 2304) return;
    int oc = idx / 2304, rem = idx - oc * 2304;
    int tap = rem >> 8, c = rem & 255;
    o[idx] = f2bf(w[oc * 2304 + c * 9 + tap]);
}
__global__ void prep_w1(const float* __restrict__ w, u16* __restrict__ o)
{
    int idx = blockIdx.x * 256 + threadIdx.x;
    if (idx < 65536) o[idx] = f2bf(w[idx]);
}
__global__ void prep_bn(const float* gk, const float* bk, const float* mk, const float* vk,
                        const float* gs, const float* bs, const float* ms, const float* vs,
                        const float* gh, const float* bh, const float* mh, const float* vh,
                        const float* bh2,
                        float* sk, float* tk, float* ss, float* ts,
                        float* sh, float* th, float* s5, float* t5)
{
    int i = threadIdx.x;
    float iv;
    iv = rsqrtf(vk[i] + EPS_BN) * gk[i]; sk[i] = iv; tk[i] = bk[i] - mk[i] * iv;
    iv = rsqrtf(vs[i] + EPS_BN) * gs[i]; ss[i] = iv; ts[i] = bs[i] - ms[i] * iv;
    iv = rsqrtf(vh[i] + EPS_BN) * gh[i]; sh[i] = iv; th[i] = bh[i] - mh[i] * iv;
    s5[i] = 1.f; t5[i] = bh2[i];
}

// ---------------------------------------------------------------------------
extern "C" void kernel_launch(void* const* d_in, const int* in_sizes, int n_in,
                              void* d_out, int out_size, void* d_ws, size_t ws_size,
                              hipStream_t stream)
{
    const float* in_kernel = (const float*)d_in[0];
    const float* in_search = (const float*)d_in[1];
    const float* wk  = (const float*)d_in[2];
    const float* gk  = (const float*)d_in[3];
    const float* bk  = (const float*)d_in[4];
    const float* mk  = (const float*)d_in[5];
    const float* vk  = (const float*)d_in[6];
    const float* wsw = (const float*)d_in[7];
    const float* gs  = (const float*)d_in[8];
    const float* bs  = (const float*)d_in[9];
    const float* ms  = (const float*)d_in[10];
    const float* vs  = (const float*)d_in[11];
    const float* wh1 = (const float*)d_in[12];
    const float* gh  = (const float*)d_in[13];
    const float* bh  = (const float*)d_in[14];
    const float* mh  = (const float*)d_in[15];
    const float* vh  = (const float*)d_in[16];
    const float* wh2 = (const float*)d_in[17];
    const float* bh2 = (const float*)d_in[18];
    float* out = (float*)d_out;

    char* w = (char*)d_ws;
    u16* Wk2 = (u16*)w;  w += 1179648;      // 256*2304 bf16
    u16* Ws2 = (u16*)w;  w += 1179648;
    u16* Wh1 = (u16*)w;  w += 131072;       // 256*256 bf16
    u16* Wh2 = (u16*)w;  w += 131072;
    float* sk = (float*)w; w += 1024;
    float* tk = (float*)w; w += 1024;
    float* ss = (float*)w; w += 1024;
    float* ts = (float*)w; w += 1024;
    float* sh = (float*)w; w += 1024;
    float* th = (float*)w; w += 1024;
    float* s5 = (float*)w; w += 1024;
    float* t5 = (float*)w; w += 1024;
    u16* kfeat = (u16*)w; w += 1638400;     // 128*25*256 bf16
    u16* sfeat = (u16*)w; w += 55115776;    // 128*841*256 bf16
    u16* feat  = (u16*)w; w += 40960000;    // 128*625*256 bf16
    u16* ktr   = (u16*)w; w += 3211264;     // 128*49*256 bf16 (NHWC kernel input)
    u16* strA  = (u16*)w; w += 62980096;    // 128*961*256 bf16 (NHWC search input)
    u16* hbuf  = strA;                      // alias: strA dead after stage 2

    // input transposes NCHW fp32 -> NHWC bf16
    tr_nchw_nhwc<<<(128 * 961 + 255) / 256, 256, 0, stream>>>(in_search, strA, 961, 128 * 961);
    tr_nchw_nhwc<<<(128 * 49 + 255) / 256, 256, 0, stream>>>(in_kernel, ktr, 49, 128 * 49);

    prep_w3<<<2304, 256, 0, stream>>>(wk,  Wk2);
    prep_w3<<<2304, 256, 0, stream>>>(wsw, Ws2);
    prep_w1<<<256, 256, 0, stream>>>(wh1, Wh1);
    prep_w1<<<256, 256, 0, stream>>>(wh2, Wh2);
    prep_bn<<<1, 256, 0, stream>>>(gk, bk, mk, vk, gs, bs, ms, vs, gh, bh, mh, vh,
                                   bh2, sk, tk, ss, ts, sh, th, s5, t5);

    // stage 1: kernel tower  -> kfeat NHWC [128*25, 256]
    conv_gemm<9, true, u16, true><<<dim3(2, 25), 256, 0, stream>>>(
        ktr, Wk2, sk, tk, kfeat, 7, 7, 5, 5);
    // stage 2: search tower  -> sfeat NHWC [128*841, 256]
    conv_gemm<9, true, u16, true><<<dim3(2, 841), 256, 0, stream>>>(
        strA, Ws2, ss, ts, sfeat, 31, 31, 29, 29);
    // stage 3: depthwise xcorr -> feat NHWC [128*625, 256]
    xcorr_kernel<<<128 * 25, 256, 0, stream>>>(sfeat, kfeat, feat);
    // stage 4: head 1x1 + BN + ReLU -> hbuf NHWC
    conv_gemm<1, true, u16, true><<<dim3(2, 625), 256, 0, stream>>>(
        feat, Wh1, sh, th, hbuf, 25, 25, 25, 25);
    // stage 5: head 1x1 + bias -> out NCHW fp32
    conv_gemm<1, false, float, false><<<dim3(2, 625), 256, 0, stream>>>(
        hbuf, Wh2, s5, t5, out, 25, 25, 25, 25);

    (void)in_sizes; (void)n_in; (void)out_size; (void)ws_size;
}